// Round 6
// baseline (339.821 us; speedup 1.0000x reference)
//
#include <hip/hip_runtime.h>
#include <hip/hip_bf16.h>
#include <cstdint>
#include <cstddef>

// Shapes: B=2, S=512, C=25, H=768, 2H=1536, 3H=2304, 4H=3072
#define BB 2
#define SS 512
#define CC 25
#define HH 768
#define H2 1536
#define H3 2304
#define H4 3072
// chunked layout: [kc][row][8] bf16, kc = k/8
#define XC_STRIDE ((size_t)96 * 512 * 8)   // per-bc X slab, 96 chunks x 512 rows

typedef __attribute__((ext_vector_type(8))) short bf16x8;
typedef __attribute__((ext_vector_type(4))) float f32x4;

#define DEVINL static __device__ __forceinline__

DEVINL unsigned short f2bf(float f) {
  union { float f; unsigned u; } v; v.f = f;
  unsigned r = v.u + 0x7FFF + ((v.u >> 16) & 1);  // RNE
  return (unsigned short)(r >> 16);
}
DEVINL float bf2f(unsigned short b) {
  union { unsigned u; float f; } v; v.u = ((unsigned)b) << 16; return v.f;
}

DEVINL void async16(const void* g, void* l) {
  __builtin_amdgcn_global_load_lds(
      (const __attribute__((address_space(1))) void*)g,
      (__attribute__((address_space(3))) void*)l, 16, 0, 0);
}

// ---------------- layout/cast kernels ----------------

// f32 row-major [R][K] -> bf16 chunked [K/8][RP][8]; rows clamped (dup last).
// grid (K/32, RP/32), block (32,4)
__global__ void k_cast_chunk(const float* __restrict__ in,
                             unsigned short* __restrict__ out,
                             int R, int K, int RP) {
  __shared__ float tile[32][33];
  int k0 = blockIdx.x * 32, r0 = blockIdx.y * 32;
  int tx = threadIdx.x, ty = threadIdx.y;
#pragma unroll
  for (int i = 0; i < 8; i++) {
    int r = r0 + ty + i * 4;
    int rr = min(r, R - 1);
    tile[ty + i * 4][tx] = in[(size_t)rr * K + k0 + tx];
  }
  __syncthreads();
  bf16x8 o;
#pragma unroll
  for (int j = 0; j < 8; j++) o[j] = (short)f2bf(tile[tx][ty * 8 + j]);
  *(bf16x8*)&out[((size_t)((k0 >> 3) + ty) * RP + r0 + tx) * 8] = o;
}

// weight f32 [Hd][N] -> bf16 chunked [Hd/8][N][8].  grid (N/64, Hd/32), block 256
__global__ void k_chunkW(const float* __restrict__ in,
                         unsigned short* __restrict__ out, int N, int Hd) {
  int tid = threadIdx.x;
  int f = blockIdx.x * 64 + (tid & 63);
  int hc = blockIdx.y * 4 + (tid >> 6);
  bf16x8 o;
#pragma unroll
  for (int j = 0; j < 8; j++)
    o[j] = (short)f2bf(in[(size_t)(hc * 8 + j) * N + f]);
  *(bf16x8*)&out[((size_t)hc * N + f) * 8] = o;
}

__global__ void k_zero_f32(float* __restrict__ p, int n) {
  int i = blockIdx.x * 256 + threadIdx.x;
  if (i < n) p[i] = 0.f;
}

// lp_f32 [50][1536] + bl -> LP chunked [192][64][8]
__global__ void k_lp_finish(const float* __restrict__ lp_f32,
                            const float* __restrict__ bl,
                            unsigned short* __restrict__ lpC, int n) {
  int i = blockIdx.x * 256 + threadIdx.x;
  if (i >= n) return;
  int col = i % H2, row = i / H2;
  float v = lp_f32[i] + bl[col];
  lpC[((size_t)(col >> 3) * 64 + row) * 8 + (col & 7)] = f2bf(v);
}

// tp_f32 [1024][1536] + bt -> TP chunked [192][1024][8]
__global__ void k_tp_finish(const float* __restrict__ tp_f32,
                            const float* __restrict__ bt,
                            unsigned short* __restrict__ tpC, int n) {
  int i = blockIdx.x * 256 + threadIdx.x;
  if (i >= n) return;
  int col = i % H2, row = i / H2;
  float v = tp_f32[i] + bt[col];
  tpC[((size_t)(col >> 3) * 1024 + row) * 8 + (col & 7)] = f2bf(v);
}

// X chunked: XC[bc][hc][s][8] = tb_chunk(96+hc)[b*512+s] * lb_chunk(96+hc)[bc]
// grid (192, 50), block 256
__global__ void k_make_x(const unsigned short* __restrict__ TP,
                         const unsigned short* __restrict__ LP,
                         unsigned short* __restrict__ XC) {
  int hc = blockIdx.x >> 1;
  int s = (blockIdx.x & 1) * 256 + threadIdx.x;
  int bc = blockIdx.y;
  int b = bc / CC;
  bf16x8 tv = *(const bf16x8*)&TP[((size_t)(96 + hc) * 1024 + b * 512 + s) * 8];
  bf16x8 lv = *(const bf16x8*)&LP[((size_t)(96 + hc) * 64 + bc) * 8];
  bf16x8 o;
#pragma unroll
  for (int j = 0; j < 8; j++)
    o[j] = (short)f2bf(bf2f((unsigned short)tv[j]) * bf2f((unsigned short)lv[j]));
  *(bf16x8*)&XC[(size_t)bc * XC_STRIDE + ((size_t)hc * 512 + s) * 8] = o;
}

__global__ void k_init_out(float* __restrict__ out, const float* __restrict__ b2, int n) {
  int i = blockIdx.x * 256 + threadIdx.x;
  if (i < n) out[i] = b2[i % 3];
}

// ---------------- 128x128 GEMM, BK=64, chunked operands ----------------
// A chunked [kc][NRA][8] (rows clamp to MA), B chunked [kc][NRB][8].
// MODE 1: f32 row-major Cf[row*ldc+col] = acc
// MODE 2: scorer epilogue (A = XC slab per bc, M local 512)
// MODE 3: atomicAdd f32 row-major (split-K over blockIdx.z)
template <int MODE>
__global__ __launch_bounds__(256, 4) void gemmC(
    const unsigned short* __restrict__ A, int NRA, int MA,
    const unsigned short* __restrict__ Bt, int NRB,
    int Klen,
    unsigned short* __restrict__ Cbf, float* __restrict__ Cf, int ldc,
    const float* __restrict__ bias,
    const float* __restrict__ base, const float* __restrict__ al,
    const float* __restrict__ b1, const float* __restrict__ W2,
    float* __restrict__ out) {
  __shared__ __align__(16) unsigned short As[8 * 128 * 8];  // [kc(8)][row(128)][8]
  __shared__ __align__(16) unsigned short Bs[8 * 128 * 8];

  const int tid = threadIdx.x;
  const int lane = tid & 63;
  const int wave = tid >> 6;
  const int q = lane >> 4;
  const int li = lane & 15;
  const int wm = (wave >> 1) * 64;
  const int wn = (wave & 1) * 64;

  const int n0 = blockIdx.x * 128;
  int m0, bc = 0;
  const unsigned short* Ab = A;
  if (MODE == 2) {
    bc = blockIdx.y >> 2;
    m0 = (blockIdx.y & 3) * 128;
    Ab = A + (size_t)bc * XC_STRIDE;
  } else {
    m0 = blockIdx.y * 128;
  }
  const int kc_base = (MODE == 3) ? blockIdx.z * (Klen >> 3) : 0;

  f32x4 acc[4][4];
#pragma unroll
  for (int i = 0; i < 4; i++)
#pragma unroll
    for (int j = 0; j < 4; j++) acc[i][j] = (f32x4){0.f, 0.f, 0.f, 0.f};

  // staging: slot = j*256+tid -> kc = slot>>7, r = slot&127; LDS offset slot*16B
  int sr[4], skc[4], sra[4];
#pragma unroll
  for (int j = 0; j < 4; j++) {
    int slot = j * 256 + tid;
    skc[j] = slot >> 7;
    sr[j] = slot & 127;
    sra[j] = min(m0 + sr[j], MA - 1);
  }

  auto stage = [&](int kciter) {
#pragma unroll
    for (int j = 0; j < 4; j++) {
      int slot = j * 256 + tid;
      async16(Ab + ((size_t)(kciter + skc[j]) * NRA + sra[j]) * 8,
              (char*)As + slot * 16);
      async16(Bt + ((size_t)(kciter + skc[j]) * NRB + n0 + sr[j]) * 8,
              (char*)Bs + slot * 16);
    }
  };

  stage(kc_base);
  const int NI = Klen / 64;
  for (int it = 0; it < NI; it++) {
    __syncthreads();  // stage landed
#pragma unroll
    for (int ks = 0; ks < 2; ks++) {
      bf16x8 af[4], bb[4];
#pragma unroll
      for (int mi = 0; mi < 4; mi++)
        af[mi] = *(const bf16x8*)&As[((ks * 4 + q) * 128 + wm + mi * 16 + li) * 8];
#pragma unroll
      for (int ni = 0; ni < 4; ni++)
        bb[ni] = *(const bf16x8*)&Bs[((ks * 4 + q) * 128 + wn + ni * 16 + li) * 8];
#pragma unroll
      for (int mi = 0; mi < 4; mi++)
#pragma unroll
        for (int ni = 0; ni < 4; ni++)
          acc[mi][ni] = __builtin_amdgcn_mfma_f32_16x16x32_bf16(
              af[mi], bb[ni], acc[mi][ni], 0, 0, 0);
    }
    __syncthreads();  // all reads done
    if (it + 1 < NI) stage(kc_base + (it + 1) * 8);
  }

  // ---------------- epilogues ----------------
  if (MODE == 1) {
#pragma unroll
    for (int mi = 0; mi < 4; mi++)
#pragma unroll
      for (int rr = 0; rr < 4; rr++) {
        int row = m0 + wm + mi * 16 + q * 4 + rr;
#pragma unroll
        for (int ni = 0; ni < 4; ni++) {
          int col = n0 + wn + ni * 16 + li;
          Cf[(size_t)row * ldc + col] = acc[mi][ni][rr];
        }
      }
  } else if (MODE == 3) {
#pragma unroll
    for (int mi = 0; mi < 4; mi++)
#pragma unroll
      for (int rr = 0; rr < 4; rr++) {
        int row = m0 + wm + mi * 16 + q * 4 + rr;
        if (row < MA) {
#pragma unroll
          for (int ni = 0; ni < 4; ni++) {
            int col = n0 + wn + ni * 16 + li;
            atomicAdd(&Cf[(size_t)row * ldc + col], acc[mi][ni][rr]);
          }
        }
      }
  } else {
    // MODE 2: scorer. E = acc + base + al + b1; relu; out += E @ W2 (MFMA)
    const int b = bc / CC, c = bc % CC;
    int fcol[4];
    float alb[4];
#pragma unroll
    for (int ni = 0; ni < 4; ni++) {
      int f = n0 + wn + ni * 16 + li;
      fcol[ni] = f;
      alb[ni] = al[(size_t)bc * H4 + f] + b1[f];
    }
    // W2 B-fragments: lane holds W2[k=q*8+j (f-local)][n=li], li<3 real
    bf16x8 w2f[2];
#pragma unroll
    for (int ks = 0; ks < 2; ks++)
#pragma unroll
      for (int jj = 0; jj < 8; jj++) {
        int f = n0 + wn + ks * 32 + q * 8 + jj;
        float v = (li < 3) ? W2[(size_t)f * 3 + li] : 0.f;
        w2f[ks][jj] = (short)f2bf(v);
      }
    // per-wave LDS scratch: 16 rows x (64+8) bf16, stride 72
    unsigned short* Ew = (unsigned short*)((char*)As + wave * 2304);

#pragma unroll
    for (int mi = 0; mi < 4; mi++) {
      float bs[4][4];
#pragma unroll
      for (int rr = 0; rr < 4; rr++) {
        int s_l = m0 + wm + mi * 16 + q * 4 + rr;
        const float* bp = base + (size_t)(b * SS + s_l) * H4;
#pragma unroll
        for (int ni = 0; ni < 4; ni++) bs[ni][rr] = bp[fcol[ni]];
      }
#pragma unroll
      for (int rr = 0; rr < 4; rr++)
#pragma unroll
        for (int ni = 0; ni < 4; ni++) {
          float v = acc[mi][ni][rr] + bs[ni][rr] + alb[ni];
          v = fmaxf(v, 0.f);
          Ew[(q * 4 + rr) * 72 + ni * 16 + li] = f2bf(v);
        }
      f32x4 oc = (f32x4){0.f, 0.f, 0.f, 0.f};
#pragma unroll
      for (int ks = 0; ks < 2; ks++) {
        bf16x8 ef = *(const bf16x8*)&Ew[li * 72 + ks * 32 + q * 8];
        oc = __builtin_amdgcn_mfma_f32_16x16x32_bf16(ef, w2f[ks], oc, 0, 0, 0);
      }
#pragma unroll
      for (int rr = 0; rr < 4; rr++) {
        int s_l = m0 + wm + mi * 16 + q * 4 + rr;
        if (li < 3)
          atomicAdd(&out[((size_t)(b * SS + s_l) * CC + c) * 3 + li], oc[rr]);
      }
    }
  }
}

// ---------------- host launch ----------------

extern "C" void kernel_launch(void* const* d_in, const int* in_sizes, int n_in,
                              void* d_out, int out_size, void* d_ws, size_t ws_size,
                              hipStream_t stream) {
  (void)in_sizes; (void)n_in; (void)ws_size;
  const float* token = (const float*)d_in[0];
  const float* label = (const float*)d_in[1];
  const float* Wt    = (const float*)d_in[2];
  const float* bt    = (const float*)d_in[3];
  const float* Wl    = (const float*)d_in[4];
  const float* bl    = (const float*)d_in[5];
  const float* W1    = (const float*)d_in[6];
  const float* b1    = (const float*)d_in[7];
  const float* W2    = (const float*)d_in[8];
  const float* b2    = (const float*)d_in[9];
  float* out = (float*)d_out;

  char* p = (char*)d_ws;
  auto alloc = [&](size_t bytes) {
    char* r = p;
    p += (bytes + 255) & ~(size_t)255;
    return r;
  };
  unsigned short* TC  = (unsigned short*)alloc((size_t)96 * 1024 * 8 * 2);
  unsigned short* LC  = (unsigned short*)alloc((size_t)96 * 64 * 8 * 2);
  unsigned short* WtC = (unsigned short*)alloc((size_t)96 * 1536 * 8 * 2);
  unsigned short* WlC = (unsigned short*)alloc((size_t)96 * 1536 * 8 * 2);
  unsigned short* W1C = (unsigned short*)alloc((size_t)288 * 3072 * 8 * 2);
  unsigned short* TP  = (unsigned short*)alloc((size_t)192 * 1024 * 8 * 2);
  unsigned short* LP  = (unsigned short*)alloc((size_t)192 * 64 * 8 * 2);
  unsigned short* XC  = (unsigned short*)alloc((size_t)CC * BB * XC_STRIDE * 2);
  // contiguous f32 scratch, zeroed in one kernel:
  float* base   = (float*)alloc((size_t)BB * SS * H4 * 4);   // 3145728
  float* al     = (float*)alloc((size_t)BB * CC * H4 * 4);   // 153600
  float* lp_f32 = (float*)alloc((size_t)BB * CC * H2 * 4);   // 76800
  float* tp_f32 = (float*)alloc((size_t)BB * SS * H2 * 4);   // 1572864

  const int nBASE = BB * SS * H4;
  const int nAL = BB * CC * H4;
  const int nLP = BB * CC * H2;
  const int nTP = BB * SS * H2;
  const int nzero = nBASE + nAL + nLP + nTP;

  // layout prep
  k_cast_chunk<<<dim3(24, 32), dim3(32, 4), 0, stream>>>(token, TC, 1024, HH, 1024);
  k_cast_chunk<<<dim3(24, 2), dim3(32, 4), 0, stream>>>(label, LC, 50, HH, 64);
  k_chunkW<<<dim3(24, 24), 256, 0, stream>>>(Wt, WtC, H2, HH);
  k_chunkW<<<dim3(24, 24), 256, 0, stream>>>(Wl, WlC, H2, HH);
  k_chunkW<<<dim3(48, 72), 256, 0, stream>>>(W1, W1C, H4, H3);
  k_zero_f32<<<(nzero + 255) / 256, 256, 0, stream>>>(base, nzero);

  // G1: tp_f32 += T @ Wt  (M=1024, N=1536, split-K 4)
  gemmC<3><<<dim3(12, 8, 4), 256, 0, stream>>>(
      TC, 1024, 1024, WtC, H2, HH / 4, nullptr, tp_f32, H2, nullptr,
      nullptr, nullptr, nullptr, nullptr, nullptr);
  k_tp_finish<<<(nTP + 255) / 256, 256, 0, stream>>>(tp_f32, bt, TP, nTP);

  // G2: lp_f32 += L @ Wl  (M=50, split-K 4)
  gemmC<3><<<dim3(12, 1, 4), 256, 0, stream>>>(
      LC, 64, 50, WlC, H2, HH / 4, nullptr, lp_f32, H2, nullptr,
      nullptr, nullptr, nullptr, nullptr, nullptr);
  k_lp_finish<<<(nLP + 255) / 256, 256, 0, stream>>>(lp_f32, bl, LP, nLP);

  // G4: al += la @ W1l  (M=50, split-K 4); B = W1 chunks 96..191
  gemmC<3><<<dim3(24, 1, 4), 256, 0, stream>>>(
      LP, 64, 50, W1C + (size_t)96 * H4 * 8, H4, HH / 4, nullptr, al, H4, nullptr,
      nullptr, nullptr, nullptr, nullptr, nullptr);

  // G3: base += ta @ W1t  (M=1024, N=3072, split-K 4); A = TP chunks 0..95
  gemmC<3><<<dim3(24, 8, 4), 256, 0, stream>>>(
      TP, 1024, 1024, W1C, H4, HH / 4, nullptr, base, H4, nullptr,
      nullptr, nullptr, nullptr, nullptr, nullptr);

  // X chunked
  k_make_x<<<dim3(192, 50), 256, 0, stream>>>(TP, LP, XC);

  k_init_out<<<(out_size + 255) / 256, 256, 0, stream>>>(out, b2, out_size);

  // G5: scorer, grid (24 n, 200 m = 50 bc x 4 s-tiles), n fastest
  gemmC<2><<<dim3(24, 200), 256, 0, stream>>>(
      XC, 512, 512, W1C + (size_t)192 * H4 * 8, H4, HH, nullptr, nullptr, 0,
      nullptr, base, al, b1, W2, out);
}

// Round 7
// 336.459 us; speedup vs baseline: 1.0100x; 1.0100x over previous
//
#include <hip/hip_runtime.h>
#include <hip/hip_bf16.h>
#include <cstdint>
#include <cstddef>

// Shapes: B=2, S=512, C=25, H=768, 2H=1536, 3H=2304, 4H=3072
#define BB 2
#define SS 512
#define CC 25
#define HH 768
#define H2 1536
#define H3 2304
#define H4 3072
// chunked layout: [kc][row][8] bf16, kc = k/8
#define XC_STRIDE ((size_t)96 * 512 * 8)   // per-bc X slab, 96 chunks x 512 rows

typedef __attribute__((ext_vector_type(8))) short bf16x8;
typedef __attribute__((ext_vector_type(4))) float f32x4;

#define DEVINL static __device__ __forceinline__

DEVINL unsigned short f2bf(float f) {
  union { float f; unsigned u; } v; v.f = f;
  unsigned r = v.u + 0x7FFF + ((v.u >> 16) & 1);  // RNE
  return (unsigned short)(r >> 16);
}
DEVINL float bf2f(unsigned short b) {
  union { unsigned u; float f; } v; v.u = ((unsigned)b) << 16; return v.f;
}

DEVINL void async16(const void* g, void* l) {
  __builtin_amdgcn_global_load_lds(
      (const __attribute__((address_space(1))) void*)g,
      (__attribute__((address_space(3))) void*)l, 16, 0, 0);
}

// ---------------- layout/cast kernels ----------------

// f32 row-major [R][K] -> bf16 chunked [K/8][RP][8]; rows clamped (dup last).
// grid (K/32, RP/32), block (32,4)
__global__ void k_cast_chunk(const float* __restrict__ in,
                             unsigned short* __restrict__ out,
                             int R, int K, int RP) {
  __shared__ float tile[32][33];
  int k0 = blockIdx.x * 32, r0 = blockIdx.y * 32;
  int tx = threadIdx.x, ty = threadIdx.y;
#pragma unroll
  for (int i = 0; i < 8; i++) {
    int r = r0 + ty + i * 4;
    int rr = min(r, R - 1);
    tile[ty + i * 4][tx] = in[(size_t)rr * K + k0 + tx];
  }
  __syncthreads();
  bf16x8 o;
#pragma unroll
  for (int j = 0; j < 8; j++) o[j] = (short)f2bf(tile[tx][ty * 8 + j]);
  *(bf16x8*)&out[((size_t)((k0 >> 3) + ty) * RP + r0 + tx) * 8] = o;
}

// weight f32 [Hd][N] -> bf16 chunked [Hd/8][N][8].  grid (N/64, Hd/32), block 256
__global__ void k_chunkW(const float* __restrict__ in,
                         unsigned short* __restrict__ out, int N, int Hd) {
  int tid = threadIdx.x;
  int f = blockIdx.x * 64 + (tid & 63);
  int hc = blockIdx.y * 4 + (tid >> 6);
  bf16x8 o;
#pragma unroll
  for (int j = 0; j < 8; j++)
    o[j] = (short)f2bf(in[(size_t)(hc * 8 + j) * N + f]);
  *(bf16x8*)&out[((size_t)hc * N + f) * 8] = o;
}

__global__ void k_zero_f32(float* __restrict__ p, int n) {
  int i = blockIdx.x * 256 + threadIdx.x;
  if (i < n) p[i] = 0.f;
}

// lp_f32 [50][1536] + bl -> LP chunked [192][64][8]
__global__ void k_lp_finish(const float* __restrict__ lp_f32,
                            const float* __restrict__ bl,
                            unsigned short* __restrict__ lpC, int n) {
  int i = blockIdx.x * 256 + threadIdx.x;
  if (i >= n) return;
  int col = i % H2, row = i / H2;
  float v = lp_f32[i] + bl[col];
  lpC[((size_t)(col >> 3) * 64 + row) * 8 + (col & 7)] = f2bf(v);
}

// X chunked: XC[bc][hc][s][8] = tb_chunk(96+hc)[b*512+s] * lb_chunk(96+hc)[bc]
// grid (192, 50), block 256
__global__ void k_make_x(const unsigned short* __restrict__ TP,
                         const unsigned short* __restrict__ LP,
                         unsigned short* __restrict__ XC) {
  int hc = blockIdx.x >> 1;
  int s = (blockIdx.x & 1) * 256 + threadIdx.x;
  int bc = blockIdx.y;
  int b = bc / CC;
  bf16x8 tv = *(const bf16x8*)&TP[((size_t)(96 + hc) * 1024 + b * 512 + s) * 8];
  bf16x8 lv = *(const bf16x8*)&LP[((size_t)(96 + hc) * 64 + bc) * 8];
  bf16x8 o;
#pragma unroll
  for (int j = 0; j < 8; j++)
    o[j] = (short)f2bf(bf2f((unsigned short)tv[j]) * bf2f((unsigned short)lv[j]));
  *(bf16x8*)&XC[(size_t)bc * XC_STRIDE + ((size_t)hc * 512 + s) * 8] = o;
}

__global__ void k_init_out(float* __restrict__ out, const float* __restrict__ b2, int n) {
  int i = blockIdx.x * 256 + threadIdx.x;
  if (i < n) out[i] = b2[i % 3];
}

// ---------------- 128x128 GEMM, BK=64, chunked operands ----------------
// A chunked [kc][NRA][8] (rows clamp to MA), B chunked [kc][NRB][8].
// MODE 0: bf16 chunked out + bias
// MODE 1: f32 row-major Cf[row*ldc+col] = acc
// MODE 3: atomicAdd f32 row-major (split-K over blockIdx.z)
template <int MODE>
__global__ __launch_bounds__(256, 4) void gemmC(
    const unsigned short* __restrict__ A, int NRA, int MA,
    const unsigned short* __restrict__ Bt, int NRB,
    int Klen,
    unsigned short* __restrict__ Cbf, float* __restrict__ Cf, int ldc,
    const float* __restrict__ bias) {
  __shared__ __align__(16) unsigned short As[8 * 128 * 8];  // [kc(8)][row(128)][8]
  __shared__ __align__(16) unsigned short Bs[8 * 128 * 8];

  const int tid = threadIdx.x;
  const int lane = tid & 63;
  const int wave = tid >> 6;
  const int q = lane >> 4;
  const int li = lane & 15;
  const int wm = (wave >> 1) * 64;
  const int wn = (wave & 1) * 64;

  const int n0 = blockIdx.x * 128;
  const int m0 = blockIdx.y * 128;
  const int kc_base = (MODE == 3) ? blockIdx.z * (Klen >> 3) : 0;

  f32x4 acc[4][4];
#pragma unroll
  for (int i = 0; i < 4; i++)
#pragma unroll
    for (int j = 0; j < 4; j++) acc[i][j] = (f32x4){0.f, 0.f, 0.f, 0.f};

  int sr[4], skc[4], sra[4];
#pragma unroll
  for (int j = 0; j < 4; j++) {
    int slot = j * 256 + tid;
    skc[j] = slot >> 7;
    sr[j] = slot & 127;
    sra[j] = min(m0 + sr[j], MA - 1);
  }

  auto stage = [&](int kciter) {
#pragma unroll
    for (int j = 0; j < 4; j++) {
      int slot = j * 256 + tid;
      async16(A + ((size_t)(kciter + skc[j]) * NRA + sra[j]) * 8,
              (char*)As + slot * 16);
      async16(Bt + ((size_t)(kciter + skc[j]) * NRB + n0 + sr[j]) * 8,
              (char*)Bs + slot * 16);
    }
  };

  stage(kc_base);
  const int NI = Klen / 64;
  for (int it = 0; it < NI; it++) {
    __syncthreads();
#pragma unroll
    for (int ks = 0; ks < 2; ks++) {
      bf16x8 af[4], bb[4];
#pragma unroll
      for (int mi = 0; mi < 4; mi++)
        af[mi] = *(const bf16x8*)&As[((ks * 4 + q) * 128 + wm + mi * 16 + li) * 8];
#pragma unroll
      for (int ni = 0; ni < 4; ni++)
        bb[ni] = *(const bf16x8*)&Bs[((ks * 4 + q) * 128 + wn + ni * 16 + li) * 8];
#pragma unroll
      for (int mi = 0; mi < 4; mi++)
#pragma unroll
        for (int ni = 0; ni < 4; ni++)
          acc[mi][ni] = __builtin_amdgcn_mfma_f32_16x16x32_bf16(
              af[mi], bb[ni], acc[mi][ni], 0, 0, 0);
    }
    __syncthreads();
    if (it + 1 < NI) stage(kc_base + (it + 1) * 8);
  }

  if (MODE == 0) {
#pragma unroll
    for (int mi = 0; mi < 4; mi++)
#pragma unroll
      for (int rr = 0; rr < 4; rr++) {
        int row = m0 + wm + mi * 16 + q * 4 + rr;
#pragma unroll
        for (int ni = 0; ni < 4; ni++) {
          int col = n0 + wn + ni * 16 + li;
          Cbf[((size_t)(col >> 3) * ldc + row) * 8 + (col & 7)] =
              f2bf(acc[mi][ni][rr] + bias[col]);
        }
      }
  } else if (MODE == 1) {
#pragma unroll
    for (int mi = 0; mi < 4; mi++)
#pragma unroll
      for (int rr = 0; rr < 4; rr++) {
        int row = m0 + wm + mi * 16 + q * 4 + rr;
#pragma unroll
        for (int ni = 0; ni < 4; ni++) {
          int col = n0 + wn + ni * 16 + li;
          Cf[(size_t)row * ldc + col] = acc[mi][ni][rr];
        }
      }
  } else {
#pragma unroll
    for (int mi = 0; mi < 4; mi++)
#pragma unroll
      for (int rr = 0; rr < 4; rr++) {
        int row = m0 + wm + mi * 16 + q * 4 + rr;
        if (row < MA) {
#pragma unroll
          for (int ni = 0; ni < 4; ni++) {
            int col = n0 + wn + ni * 16 + li;
            atomicAdd(&Cf[(size_t)row * ldc + col], acc[mi][ni][rr]);
          }
        }
      }
  }
}

// ---------------- G5: 256x256 tile, 512 threads, BK=64 ----------------
// 8 waves as 2m x 4n; wave-tile 128m x 64n; acc[8][4] f32x4 = 128 VGPR.
// LDS 64 KB single-buffer; grid (12 n-tiles, 100 = 50 bc x 2 m-tiles).
__global__ __launch_bounds__(512, 2) void gemm512_scorer(
    const unsigned short* __restrict__ XCp,  // per-bc slabs [96][512][8]
    const unsigned short* __restrict__ Bt,   // W1p chunked [96][3072][8]
    const float* __restrict__ base,          // (2*512) x 3072 f32
    const float* __restrict__ al,            // 50 x 3072 f32
    const float* __restrict__ b1,
    const float* __restrict__ W2,            // 3072 x 3
    float* __restrict__ out) {
  __shared__ __align__(16) unsigned short As[8 * 256 * 8];  // 32 KB
  __shared__ __align__(16) unsigned short Bs[8 * 256 * 8];  // 32 KB

  const int tid = threadIdx.x;              // 0..511
  const int lane = tid & 63;
  const int wave = tid >> 6;                // 0..7
  const int q = lane >> 4;
  const int li = lane & 15;
  const int wm = (wave >> 2) * 128;         // 0 / 128
  const int wn = (wave & 3) * 64;           // 0..192

  const int n0 = blockIdx.x * 256;
  const int bc = blockIdx.y >> 1;
  const int m0 = (blockIdx.y & 1) * 256;
  const unsigned short* Ab = XCp + (size_t)bc * XC_STRIDE;

  f32x4 acc[8][4];
#pragma unroll
  for (int i = 0; i < 8; i++)
#pragma unroll
    for (int j = 0; j < 4; j++) acc[i][j] = (f32x4){0.f, 0.f, 0.f, 0.f};

  // staging: slot = j*512 + tid; kc = slot>>8 (0..7); r = slot&255
  int skc[4], sr[4];
#pragma unroll
  for (int j = 0; j < 4; j++) {
    int slot = j * 512 + tid;
    skc[j] = slot >> 8;
    sr[j] = slot & 255;
  }
  auto stage = [&](int kcbase) {
#pragma unroll
    for (int j = 0; j < 4; j++) {
      int slot = j * 512 + tid;
      async16(Ab + ((size_t)(kcbase + skc[j]) * 512 + m0 + sr[j]) * 8,
              (char*)As + slot * 16);
      async16(Bt + ((size_t)(kcbase + skc[j]) * H4 + n0 + sr[j]) * 8,
              (char*)Bs + slot * 16);
    }
  };

  stage(0);
  for (int it = 0; it < 12; it++) {
    __syncthreads();  // stage landed
#pragma unroll
    for (int ks = 0; ks < 2; ks++) {
      bf16x8 af[8], bb[4];
#pragma unroll
      for (int mi = 0; mi < 8; mi++)
        af[mi] = *(const bf16x8*)&As[((ks * 4 + q) * 256 + wm + mi * 16 + li) * 8];
#pragma unroll
      for (int ni = 0; ni < 4; ni++)
        bb[ni] = *(const bf16x8*)&Bs[((ks * 4 + q) * 256 + wn + ni * 16 + li) * 8];
#pragma unroll
      for (int mi = 0; mi < 8; mi++)
#pragma unroll
        for (int ni = 0; ni < 4; ni++)
          acc[mi][ni] = __builtin_amdgcn_mfma_f32_16x16x32_bf16(
              af[mi], bb[ni], acc[mi][ni], 0, 0, 0);
    }
    __syncthreads();  // all reads done
    if (it + 1 < 12) stage((it + 1) * 8);
  }

  // epilogue: E = acc + base + al + b1; relu; out += E @ W2 via MFMA
  const int b = bc / CC, c = bc % CC;
  int fcol[4];
  float alb[4];
#pragma unroll
  for (int ni = 0; ni < 4; ni++) {
    int f = n0 + wn + ni * 16 + li;
    fcol[ni] = f;
    alb[ni] = al[(size_t)bc * H4 + f] + b1[f];
  }
  bf16x8 w2f[2];
#pragma unroll
  for (int ks = 0; ks < 2; ks++)
#pragma unroll
    for (int jj = 0; jj < 8; jj++) {
      int f = n0 + wn + ks * 32 + q * 8 + jj;
      float v = (li < 3) ? W2[(size_t)f * 3 + li] : 0.f;
      w2f[ks][jj] = (short)f2bf(v);
    }
  // per-wave LDS scratch: 16 rows x stride-72 bf16 (reuse As; all waves past
  // final barrier and frags are in registers)
  unsigned short* Ew = (unsigned short*)((char*)As + wave * 2304);

#pragma unroll
  for (int mi = 0; mi < 8; mi++) {
    float bs[4][4];
#pragma unroll
    for (int rr = 0; rr < 4; rr++) {
      int s_l = m0 + wm + mi * 16 + q * 4 + rr;
      const float* bp = base + (size_t)(b * SS + s_l) * H4;
#pragma unroll
      for (int ni = 0; ni < 4; ni++) bs[ni][rr] = bp[fcol[ni]];
    }
#pragma unroll
    for (int rr = 0; rr < 4; rr++)
#pragma unroll
      for (int ni = 0; ni < 4; ni++) {
        float v = acc[mi][ni][rr] + bs[ni][rr] + alb[ni];
        v = fmaxf(v, 0.f);
        Ew[(q * 4 + rr) * 72 + ni * 16 + li] = f2bf(v);
      }
    f32x4 oc = (f32x4){0.f, 0.f, 0.f, 0.f};
#pragma unroll
    for (int ks = 0; ks < 2; ks++) {
      bf16x8 ef = *(const bf16x8*)&Ew[li * 72 + ks * 32 + q * 8];
      oc = __builtin_amdgcn_mfma_f32_16x16x32_bf16(ef, w2f[ks], oc, 0, 0, 0);
    }
#pragma unroll
    for (int rr = 0; rr < 4; rr++) {
      int s_l = m0 + wm + mi * 16 + q * 4 + rr;
      if (li < 3)
        atomicAdd(&out[((size_t)(b * SS + s_l) * CC + c) * 3 + li], oc[rr]);
    }
  }
}

// ---------------- host launch ----------------

extern "C" void kernel_launch(void* const* d_in, const int* in_sizes, int n_in,
                              void* d_out, int out_size, void* d_ws, size_t ws_size,
                              hipStream_t stream) {
  (void)in_sizes; (void)n_in; (void)ws_size;
  const float* token = (const float*)d_in[0];
  const float* label = (const float*)d_in[1];
  const float* Wt    = (const float*)d_in[2];
  const float* bt    = (const float*)d_in[3];
  const float* Wl    = (const float*)d_in[4];
  const float* bl    = (const float*)d_in[5];
  const float* W1    = (const float*)d_in[6];
  const float* b1    = (const float*)d_in[7];
  const float* W2    = (const float*)d_in[8];
  const float* b2    = (const float*)d_in[9];
  float* out = (float*)d_out;

  char* p = (char*)d_ws;
  auto alloc = [&](size_t bytes) {
    char* r = p;
    p += (bytes + 255) & ~(size_t)255;
    return r;
  };
  unsigned short* TC  = (unsigned short*)alloc((size_t)96 * 1024 * 8 * 2);
  unsigned short* LC  = (unsigned short*)alloc((size_t)96 * 64 * 8 * 2);
  unsigned short* WtC = (unsigned short*)alloc((size_t)96 * 1536 * 8 * 2);
  unsigned short* WlC = (unsigned short*)alloc((size_t)96 * 1536 * 8 * 2);
  unsigned short* W1C = (unsigned short*)alloc((size_t)288 * 3072 * 8 * 2);
  unsigned short* TP  = (unsigned short*)alloc((size_t)192 * 1024 * 8 * 2);
  unsigned short* LP  = (unsigned short*)alloc((size_t)192 * 64 * 8 * 2);
  unsigned short* XC  = (unsigned short*)alloc((size_t)CC * BB * XC_STRIDE * 2);
  float* base   = (float*)alloc((size_t)BB * SS * H4 * 4);
  float* al     = (float*)alloc((size_t)BB * CC * H4 * 4);   // zeroed (atomics)
  float* lp_f32 = (float*)alloc((size_t)BB * CC * H2 * 4);   // zeroed (atomics)

  const int nLP = BB * CC * H2;   // 76800
  const int nAL = BB * CC * H4;   // 153600

  // layout prep
  k_cast_chunk<<<dim3(24, 32), dim3(32, 4), 0, stream>>>(token, TC, 1024, HH, 1024);
  k_cast_chunk<<<dim3(24, 2), dim3(32, 4), 0, stream>>>(label, LC, 50, HH, 64);
  k_chunkW<<<dim3(24, 24), 256, 0, stream>>>(Wt, WtC, H2, HH);
  k_chunkW<<<dim3(24, 24), 256, 0, stream>>>(Wl, WlC, H2, HH);
  k_chunkW<<<dim3(48, 72), 256, 0, stream>>>(W1, W1C, H4, H3);
  k_zero_f32<<<(nAL + nLP + 255) / 256, 256, 0, stream>>>(al, nAL + nLP);

  // G1: tp = T @ Wt + bt -> TP chunked (M=1024, N=1536, K=768)
  gemmC<0><<<dim3(12, 8), 256, 0, stream>>>(
      TC, 1024, 1024, WtC, H2, HH, TP, nullptr, 1024, bt);
  // G2: lp_f32 += L @ Wl  (M=50, split-K 4)
  gemmC<3><<<dim3(12, 1, 4), 256, 0, stream>>>(
      LC, 64, 50, WlC, H2, HH / 4, nullptr, lp_f32, H2, nullptr);
  k_lp_finish<<<(nLP + 255) / 256, 256, 0, stream>>>(lp_f32, bl, LP, nLP);
  // G4: al += la @ W1l  (M=50, split-K 4); B = W1 chunks 96..191
  gemmC<3><<<dim3(24, 1, 4), 256, 0, stream>>>(
      LP, 64, 50, W1C + (size_t)96 * H4 * 8, H4, HH / 4, nullptr, al, H4, nullptr);
  // X chunked
  k_make_x<<<dim3(192, 50), 256, 0, stream>>>(TP, LP, XC);
  // G3: base = ta @ W1t (f32 row-major); A = TP chunks 0..95
  gemmC<1><<<dim3(24, 8), 256, 0, stream>>>(
      TP, 1024, 1024, W1C, H4, HH, nullptr, base, H4, nullptr);

  k_init_out<<<(out_size + 255) / 256, 256, 0, stream>>>(out, b2, out_size);

  // G5: 256x256 scorer, grid (12 n, 100 = 50 bc x 2 m-tiles)
  gemm512_scorer<<<dim3(12, 100), 512, 0, stream>>>(
      XC, W1C + (size_t)192 * H4 * 8, base, al, b1, W2, out);
}

// Round 8
// 305.500 us; speedup vs baseline: 1.1123x; 1.1013x over previous
//
#include <hip/hip_runtime.h>
#include <hip/hip_bf16.h>
#include <cstdint>
#include <cstddef>

// Shapes: B=2, S=512, C=25, H=768, 2H=1536, 3H=2304, 4H=3072
#define BB 2
#define SS 512
#define CC 25
#define HH 768
#define H2 1536
#define H3 2304
#define H4 3072
// chunked layout: [kc][row][8] bf16, kc = k/8
#define XC_STRIDE ((size_t)96 * 512 * 8)   // per-bc X slab, 96 chunks x 512 rows

typedef __attribute__((ext_vector_type(8))) short bf16x8;
typedef __attribute__((ext_vector_type(4))) float f32x4;

#define DEVINL static __device__ __forceinline__

DEVINL unsigned short f2bf(float f) {
  union { float f; unsigned u; } v; v.f = f;
  unsigned r = v.u + 0x7FFF + ((v.u >> 16) & 1);  // RNE
  return (unsigned short)(r >> 16);
}
DEVINL float bf2f(unsigned short b) {
  union { unsigned u; float f; } v; v.u = ((unsigned)b) << 16; return v.f;
}

DEVINL void async16(const void* g, void* l) {
  __builtin_amdgcn_global_load_lds(
      (const __attribute__((address_space(1))) void*)g,
      (__attribute__((address_space(3))) void*)l, 16, 0, 0);
}

// ---------------- prep kernel 1: activations cast + out init ----------------
// bid [0,384): token [1024][768] -> TC [96][1024][8]   (24 k-tiles x 16 r-tiles)
// bid [384,408): label [50][768] -> LC [96][64][8]     (24 k-tiles x 1 r-tile)
// bid [408,708): out init = b2 broadcast (76800 elems)
__global__ void k_prep_cast(const float* __restrict__ token,
                            const float* __restrict__ label,
                            const float* __restrict__ b2,
                            unsigned short* __restrict__ TC,
                            unsigned short* __restrict__ LC,
                            float* __restrict__ out) {
  __shared__ float tile[64][33];
  const int bid = blockIdx.x;
  const int tid = threadIdx.x;
  if (bid < 408) {
    const float* in;
    unsigned short* o;
    int R, RP, kt, rt;
    if (bid < 384) {
      in = token; o = TC; R = 1024; RP = 1024; kt = bid % 24; rt = bid / 24;
    } else {
      in = label; o = LC; R = 50; RP = 64; kt = bid - 384; rt = 0;
    }
    const int k0 = kt * 32, r0 = rt * 64;
    const int tx = tid & 31, ty = tid >> 5;  // (32,8)
#pragma unroll
    for (int i = 0; i < 8; i++) {
      int r = r0 + ty + i * 8;
      tile[ty + i * 8][tx] = in[(size_t)min(r, R - 1) * HH + k0 + tx];
    }
    __syncthreads();
    const int rl = tid & 63, kcl = tid >> 6;  // 64 rows x 4 kc
    bf16x8 ov;
#pragma unroll
    for (int j = 0; j < 8; j++) ov[j] = (short)f2bf(tile[rl][kcl * 8 + j]);
    *(bf16x8*)&o[((size_t)((k0 >> 3) + kcl) * RP + r0 + rl) * 8] = ov;
  } else {
    int i = (bid - 408) * 256 + tid;
    if (i < BB * SS * CC * 3) out[i] = b2[i % 3];
  }
}

// ---------------- prep kernel 2: weights -> chunked [hc][f][8] ----------------
// bid [0,3456): W1 [2304][3072] -> W1C [288][3072][8]  (48 f-tiles x 72 hc-tiles)
// bid [3456,4032): Wt [768][1536] -> WtC [96][1536][8] (24 x 24)
// bid [4032,4608): Wl -> WlC
__global__ void k_prep_w(const float* __restrict__ Wt,
                         const float* __restrict__ Wl,
                         const float* __restrict__ W1,
                         unsigned short* __restrict__ WtC,
                         unsigned short* __restrict__ WlC,
                         unsigned short* __restrict__ W1C) {
  const int bid = blockIdx.x, tid = threadIdx.x;
  const float* in;
  unsigned short* o;
  int N, bx, by;
  if (bid < 3456) {
    in = W1; o = W1C; N = H4; bx = bid % 48; by = bid / 48;
  } else if (bid < 4032) {
    int b = bid - 3456; in = Wt; o = WtC; N = H2; bx = b % 24; by = b / 24;
  } else {
    int b = bid - 4032; in = Wl; o = WlC; N = H2; bx = b % 24; by = b / 24;
  }
  const int f = bx * 64 + (tid & 63);
  const int hc = by * 4 + (tid >> 6);
  bf16x8 ov;
#pragma unroll
  for (int j = 0; j < 8; j++)
    ov[j] = (short)f2bf(in[(size_t)(hc * 8 + j) * N + f]);
  *(bf16x8*)&o[((size_t)hc * N + f) * 8] = ov;
}

// X chunked: XC[bc][hc][s][8] = tb_chunk(96+hc)[b*512+s] * lb_chunk(96+hc)[bc]
// grid (192, 50), block 256
__global__ void k_make_x(const unsigned short* __restrict__ TP,
                         const unsigned short* __restrict__ LP,
                         unsigned short* __restrict__ XC) {
  int hc = blockIdx.x >> 1;
  int s = (blockIdx.x & 1) * 256 + threadIdx.x;
  int bc = blockIdx.y;
  int b = bc / CC;
  bf16x8 tv = *(const bf16x8*)&TP[((size_t)(96 + hc) * 1024 + b * 512 + s) * 8];
  bf16x8 lv = *(const bf16x8*)&LP[((size_t)(96 + hc) * 64 + bc) * 8];
  bf16x8 o;
#pragma unroll
  for (int j = 0; j < 8; j++)
    o[j] = (short)f2bf(bf2f((unsigned short)tv[j]) * bf2f((unsigned short)lv[j]));
  *(bf16x8*)&XC[(size_t)bc * XC_STRIDE + ((size_t)hc * 512 + s) * 8] = o;
}

// ---------------- 128x128 GEMM, BK=64, chunked operands ----------------
// A chunked [kc][NRA][8] (rows clamp to MA), B chunked [kc][NRB][8].
// MODE 0: bf16 chunked out + bias (ldc = NR of output layout), rows < MA
// MODE 1: f32 row-major Cf[row*ldc+col] = acc, rows < MA
// MODE 2: scorer epilogue (A = XC slab per bc, M local 512)
template <int MODE>
__global__ __launch_bounds__(256, 4) void gemmC(
    const unsigned short* __restrict__ A, int NRA, int MA,
    const unsigned short* __restrict__ Bt, int NRB,
    int Klen,
    unsigned short* __restrict__ Cbf, float* __restrict__ Cf, int ldc,
    const float* __restrict__ bias,
    const float* __restrict__ base, const float* __restrict__ al,
    const float* __restrict__ b1, const float* __restrict__ W2,
    float* __restrict__ out) {
  __shared__ __align__(16) unsigned short As[8 * 128 * 8];  // [kc(8)][row(128)][8]
  __shared__ __align__(16) unsigned short Bs[8 * 128 * 8];

  const int tid = threadIdx.x;
  const int lane = tid & 63;
  const int wave = tid >> 6;
  const int q = lane >> 4;
  const int li = lane & 15;
  const int wm = (wave >> 1) * 64;
  const int wn = (wave & 1) * 64;

  const int n0 = blockIdx.x * 128;
  int m0, bc = 0;
  const unsigned short* Ab = A;
  if (MODE == 2) {
    bc = blockIdx.y >> 2;
    m0 = (blockIdx.y & 3) * 128;
    Ab = A + (size_t)bc * XC_STRIDE;
  } else {
    m0 = blockIdx.y * 128;
  }

  f32x4 acc[4][4];
#pragma unroll
  for (int i = 0; i < 4; i++)
#pragma unroll
    for (int j = 0; j < 4; j++) acc[i][j] = (f32x4){0.f, 0.f, 0.f, 0.f};

  int sr[4], skc[4], sra[4];
#pragma unroll
  for (int j = 0; j < 4; j++) {
    int slot = j * 256 + tid;
    skc[j] = slot >> 7;
    sr[j] = slot & 127;
    sra[j] = min(m0 + sr[j], MA - 1);
  }

  auto stage = [&](int kciter) {
#pragma unroll
    for (int j = 0; j < 4; j++) {
      int slot = j * 256 + tid;
      async16(Ab + ((size_t)(kciter + skc[j]) * NRA + sra[j]) * 8,
              (char*)As + slot * 16);
      async16(Bt + ((size_t)(kciter + skc[j]) * NRB + n0 + sr[j]) * 8,
              (char*)Bs + slot * 16);
    }
  };

  stage(0);
  const int NI = Klen / 64;
  for (int it = 0; it < NI; it++) {
    __syncthreads();  // stage landed
#pragma unroll
    for (int ks = 0; ks < 2; ks++) {
      bf16x8 af[4], bb[4];
#pragma unroll
      for (int mi = 0; mi < 4; mi++)
        af[mi] = *(const bf16x8*)&As[((ks * 4 + q) * 128 + wm + mi * 16 + li) * 8];
#pragma unroll
      for (int ni = 0; ni < 4; ni++)
        bb[ni] = *(const bf16x8*)&Bs[((ks * 4 + q) * 128 + wn + ni * 16 + li) * 8];
#pragma unroll
      for (int mi = 0; mi < 4; mi++)
#pragma unroll
        for (int ni = 0; ni < 4; ni++)
          acc[mi][ni] = __builtin_amdgcn_mfma_f32_16x16x32_bf16(
              af[mi], bb[ni], acc[mi][ni], 0, 0, 0);
    }
    __syncthreads();  // all reads done
    if (it + 1 < NI) stage((it + 1) * 8);
  }

  // ---------------- epilogues ----------------
  if (MODE == 0) {
#pragma unroll
    for (int mi = 0; mi < 4; mi++)
#pragma unroll
      for (int rr = 0; rr < 4; rr++) {
        int row = m0 + wm + mi * 16 + q * 4 + rr;
        if (row < MA) {
#pragma unroll
          for (int ni = 0; ni < 4; ni++) {
            int col = n0 + wn + ni * 16 + li;
            Cbf[((size_t)(col >> 3) * ldc + row) * 8 + (col & 7)] =
                f2bf(acc[mi][ni][rr] + bias[col]);
          }
        }
      }
  } else if (MODE == 1) {
#pragma unroll
    for (int mi = 0; mi < 4; mi++)
#pragma unroll
      for (int rr = 0; rr < 4; rr++) {
        int row = m0 + wm + mi * 16 + q * 4 + rr;
        if (row < MA) {
#pragma unroll
          for (int ni = 0; ni < 4; ni++) {
            int col = n0 + wn + ni * 16 + li;
            Cf[(size_t)row * ldc + col] = acc[mi][ni][rr];
          }
        }
      }
  } else {
    // MODE 2: scorer. E = acc + base + al + b1; relu; out += E @ W2 (MFMA)
    const int b = bc / CC, c = bc % CC;
    int fcol[4];
    float alb[4];
#pragma unroll
    for (int ni = 0; ni < 4; ni++) {
      int f = n0 + wn + ni * 16 + li;
      fcol[ni] = f;
      alb[ni] = al[(size_t)bc * H4 + f] + b1[f];
    }
    // W2 B-fragments: lane holds W2[k=q*8+j (f-local)][n=li], li<3 real
    bf16x8 w2f[2];
#pragma unroll
    for (int ks = 0; ks < 2; ks++)
#pragma unroll
      for (int jj = 0; jj < 8; jj++) {
        int f = n0 + wn + ks * 32 + q * 8 + jj;
        float v = (li < 3) ? W2[(size_t)f * 3 + li] : 0.f;
        w2f[ks][jj] = (short)f2bf(v);
      }
    // per-wave LDS scratch: 16 rows x stride-72 bf16
    unsigned short* Ew = (unsigned short*)((char*)As + wave * 2304);

#pragma unroll
    for (int mi = 0; mi < 4; mi++) {
      float bs[4][4];
#pragma unroll
      for (int rr = 0; rr < 4; rr++) {
        int s_l = m0 + wm + mi * 16 + q * 4 + rr;
        const float* bp = base + (size_t)(b * SS + s_l) * H4;
#pragma unroll
        for (int ni = 0; ni < 4; ni++) bs[ni][rr] = bp[fcol[ni]];
      }
#pragma unroll
      for (int rr = 0; rr < 4; rr++)
#pragma unroll
        for (int ni = 0; ni < 4; ni++) {
          float v = acc[mi][ni][rr] + bs[ni][rr] + alb[ni];
          v = fmaxf(v, 0.f);
          Ew[(q * 4 + rr) * 72 + ni * 16 + li] = f2bf(v);
        }
      f32x4 oc = (f32x4){0.f, 0.f, 0.f, 0.f};
#pragma unroll
      for (int ks = 0; ks < 2; ks++) {
        bf16x8 ef = *(const bf16x8*)&Ew[li * 72 + ks * 32 + q * 8];
        oc = __builtin_amdgcn_mfma_f32_16x16x32_bf16(ef, w2f[ks], oc, 0, 0, 0);
      }
#pragma unroll
      for (int rr = 0; rr < 4; rr++) {
        int s_l = m0 + wm + mi * 16 + q * 4 + rr;
        if (li < 3)
          atomicAdd(&out[((size_t)(b * SS + s_l) * CC + c) * 3 + li], oc[rr]);
      }
    }
  }
}

// ---------------- host launch ----------------

extern "C" void kernel_launch(void* const* d_in, const int* in_sizes, int n_in,
                              void* d_out, int out_size, void* d_ws, size_t ws_size,
                              hipStream_t stream) {
  (void)in_sizes; (void)n_in; (void)ws_size; (void)out_size;
  const float* token = (const float*)d_in[0];
  const float* label = (const float*)d_in[1];
  const float* Wt    = (const float*)d_in[2];
  const float* bt    = (const float*)d_in[3];
  const float* Wl    = (const float*)d_in[4];
  const float* bl    = (const float*)d_in[5];
  const float* W1    = (const float*)d_in[6];
  const float* b1    = (const float*)d_in[7];
  const float* W2    = (const float*)d_in[8];
  const float* b2    = (const float*)d_in[9];
  float* out = (float*)d_out;

  char* p = (char*)d_ws;
  auto alloc = [&](size_t bytes) {
    char* r = p;
    p += (bytes + 255) & ~(size_t)255;
    return r;
  };
  unsigned short* TC  = (unsigned short*)alloc((size_t)96 * 1024 * 8 * 2);
  unsigned short* LC  = (unsigned short*)alloc((size_t)96 * 64 * 8 * 2);
  unsigned short* WtC = (unsigned short*)alloc((size_t)96 * 1536 * 8 * 2);
  unsigned short* WlC = (unsigned short*)alloc((size_t)96 * 1536 * 8 * 2);
  unsigned short* W1C = (unsigned short*)alloc((size_t)288 * 3072 * 8 * 2);
  unsigned short* TP  = (unsigned short*)alloc((size_t)192 * 1024 * 8 * 2);
  unsigned short* LP  = (unsigned short*)alloc((size_t)192 * 64 * 8 * 2);
  unsigned short* XC  = (unsigned short*)alloc((size_t)CC * BB * XC_STRIDE * 2);
  float* base = (float*)alloc((size_t)BB * SS * H4 * 4);
  float* al   = (float*)alloc((size_t)BB * CC * H4 * 4);

  // P1: token/label chunk-cast + out=b2 init (708 blocks)
  k_prep_cast<<<708, 256, 0, stream>>>(token, label, b2, TC, LC, out);
  // P2: Wt/Wl/W1 chunking (4608 blocks)
  k_prep_w<<<4608, 256, 0, stream>>>(Wt, Wl, W1, WtC, WlC, W1C);

  // G2: lp = L @ Wl + bl -> LP chunked (M=50, N=1536, K=768)
  gemmC<0><<<dim3(12, 1), 256, 0, stream>>>(
      LC, 64, 50, WlC, H2, HH, LP, nullptr, 64, bl,
      nullptr, nullptr, nullptr, nullptr, nullptr);
  // G1: tp = T @ Wt + bt -> TP chunked (M=1024, N=1536, K=768)
  gemmC<0><<<dim3(12, 8), 256, 0, stream>>>(
      TC, 1024, 1024, WtC, H2, HH, TP, nullptr, 1024, bt,
      nullptr, nullptr, nullptr, nullptr, nullptr);

  // X = tb .* lb, chunked slabs
  k_make_x<<<dim3(192, 50), 256, 0, stream>>>(TP, LP, XC);

  // G4: al = la @ W1l (f32 row-major, M=50, N=3072)
  gemmC<1><<<dim3(24, 1), 256, 0, stream>>>(
      LP, 64, 50, W1C + (size_t)96 * H4 * 8, H4, HH, nullptr, al, H4, nullptr,
      nullptr, nullptr, nullptr, nullptr, nullptr);
  // G3: base = ta @ W1t (f32 row-major, M=1024, N=3072)
  gemmC<1><<<dim3(24, 8), 256, 0, stream>>>(
      TP, 1024, 1024, W1C, H4, HH, nullptr, base, H4, nullptr,
      nullptr, nullptr, nullptr, nullptr, nullptr);

  // G5: scorer, grid (24 n, 200 = 50 bc x 4 s-tiles)
  gemmC<2><<<dim3(24, 200), 256, 0, stream>>>(
      XC, 512, 512, W1C + (size_t)192 * H4 * 8, H4, HH, nullptr, nullptr, 0,
      nullptr, base, al, b1, W2, out);
}

// Round 9
// 273.882 us; speedup vs baseline: 1.2408x; 1.1154x over previous
//
#include <hip/hip_runtime.h>
#include <hip/hip_bf16.h>
#include <cstdint>
#include <cstddef>

// Shapes: B=2, S=512, C=25, H=768, 2H=1536, 3H=2304, 4H=3072
#define BB 2
#define SS 512
#define CC 25
#define HH 768
#define H2 1536
#define H3 2304
#define H4 3072
// chunked layout: [kc][row][8] bf16, kc = k/8
#define XC_STRIDE ((size_t)96 * 512 * 8)   // per-bc X slab, 96 chunks x 512 rows

typedef __attribute__((ext_vector_type(8))) short bf16x8;
typedef __attribute__((ext_vector_type(4))) float f32x4;

#define DEVINL static __device__ __forceinline__

DEVINL unsigned short f2bf(float f) {
  union { float f; unsigned u; } v; v.f = f;
  unsigned r = v.u + 0x7FFF + ((v.u >> 16) & 1);  // RNE
  return (unsigned short)(r >> 16);
}
DEVINL float bf2f(unsigned short b) {
  union { unsigned u; float f; } v; v.u = ((unsigned)b) << 16; return v.f;
}

DEVINL void async16(const void* g, void* l) {
  __builtin_amdgcn_global_load_lds(
      (const __attribute__((address_space(1))) void*)g,
      (__attribute__((address_space(3))) void*)l, 16, 0, 0);
}

// ---------------- K1: all casts/chunking + out init (5316 blocks) ----------
// bid [0,384): token [1024][768] -> TC [96][1024][8]
// bid [384,408): label [50][768] -> LC [96][64][8]
// bid [408,708): out init = b2 broadcast
// bid [708,4164): W1 [2304][3072] -> W1C [288][3072][8]
// bid [4164,4740): Wt [768][1536] -> WtC [96][1536][8]
// bid [4740,5316): Wl -> WlC
__global__ void k_prep(const float* __restrict__ token,
                       const float* __restrict__ label,
                       const float* __restrict__ b2,
                       const float* __restrict__ Wt,
                       const float* __restrict__ Wl,
                       const float* __restrict__ W1,
                       unsigned short* __restrict__ TC,
                       unsigned short* __restrict__ LC,
                       float* __restrict__ out,
                       unsigned short* __restrict__ WtC,
                       unsigned short* __restrict__ WlC,
                       unsigned short* __restrict__ W1C) {
  __shared__ float tile[64][33];
  const int bid = blockIdx.x;
  const int tid = threadIdx.x;
  if (bid < 408) {
    const float* in;
    unsigned short* o;
    int R, RP, kt, rt;
    if (bid < 384) {
      in = token; o = TC; R = 1024; RP = 1024; kt = bid % 24; rt = bid / 24;
    } else {
      in = label; o = LC; R = 50; RP = 64; kt = bid - 384; rt = 0;
    }
    const int k0 = kt * 32, r0 = rt * 64;
    const int tx = tid & 31, ty = tid >> 5;
#pragma unroll
    for (int i = 0; i < 8; i++) {
      int r = r0 + ty + i * 8;
      tile[ty + i * 8][tx] = in[(size_t)min(r, R - 1) * HH + k0 + tx];
    }
    __syncthreads();
    const int rl = tid & 63, kcl = tid >> 6;
    bf16x8 ov;
#pragma unroll
    for (int j = 0; j < 8; j++) ov[j] = (short)f2bf(tile[rl][kcl * 8 + j]);
    *(bf16x8*)&o[((size_t)((k0 >> 3) + kcl) * RP + r0 + rl) * 8] = ov;
  } else if (bid < 708) {
    int i = (bid - 408) * 256 + tid;
    if (i < BB * SS * CC * 3) out[i] = b2[i % 3];
  } else {
    const int wb = bid - 708;
    const float* in;
    unsigned short* o;
    int N, bx, by;
    if (wb < 3456) {
      in = W1; o = W1C; N = H4; bx = wb % 48; by = wb / 48;
    } else if (wb < 4032) {
      int b = wb - 3456; in = Wt; o = WtC; N = H2; bx = b % 24; by = b / 24;
    } else {
      int b = wb - 4032; in = Wl; o = WlC; N = H2; bx = b % 24; by = b / 24;
    }
    const int f = bx * 64 + (tid & 63);
    const int hc = by * 4 + (tid >> 6);
    bf16x8 ov;
#pragma unroll
    for (int j = 0; j < 8; j++)
      ov[j] = (short)f2bf(in[(size_t)(hc * 8 + j) * N + f]);
    *(bf16x8*)&o[((size_t)hc * N + f) * 8] = ov;
  }
}

// ---------------- shared K-loop: 128x128 tile, K=768, chunked operands -----
DEVINL void mm_kloop(const unsigned short* __restrict__ Ab, int NRA, int MA,
                     int m0, const unsigned short* __restrict__ Bt, int NRB,
                     int n0, unsigned short* As, unsigned short* Bs,
                     f32x4 (&acc)[4][4]) {
  const int tid = threadIdx.x;
  const int lane = tid & 63;
  const int wave = tid >> 6;
  const int q = lane >> 4;
  const int li = lane & 15;
  const int wm = (wave >> 1) * 64;
  const int wn = (wave & 1) * 64;

  int sr[4], skc[4], sra[4];
#pragma unroll
  for (int j = 0; j < 4; j++) {
    int slot = j * 256 + tid;
    skc[j] = slot >> 7;
    sr[j] = slot & 127;
    sra[j] = min(m0 + sr[j], MA - 1);
  }
  auto stage = [&](int kciter) {
#pragma unroll
    for (int j = 0; j < 4; j++) {
      int slot = j * 256 + tid;
      async16(Ab + ((size_t)(kciter + skc[j]) * NRA + sra[j]) * 8,
              (char*)As + slot * 16);
      async16(Bt + ((size_t)(kciter + skc[j]) * NRB + n0 + sr[j]) * 8,
              (char*)Bs + slot * 16);
    }
  };

  stage(0);
  for (int it = 0; it < 12; it++) {
    __syncthreads();  // stage landed
#pragma unroll
    for (int ks = 0; ks < 2; ks++) {
      bf16x8 af[4], bb[4];
#pragma unroll
      for (int mi = 0; mi < 4; mi++)
        af[mi] = *(const bf16x8*)&As[((ks * 4 + q) * 128 + wm + mi * 16 + li) * 8];
#pragma unroll
      for (int ni = 0; ni < 4; ni++)
        bb[ni] = *(const bf16x8*)&Bs[((ks * 4 + q) * 128 + wn + ni * 16 + li) * 8];
#pragma unroll
      for (int mi = 0; mi < 4; mi++)
#pragma unroll
        for (int ni = 0; ni < 4; ni++)
          acc[mi][ni] = __builtin_amdgcn_mfma_f32_16x16x32_bf16(
              af[mi], bb[ni], acc[mi][ni], 0, 0, 0);
    }
    __syncthreads();  // all reads done
    if (it + 1 < 12) stage((it + 1) * 8);
  }
}

// ---------------- K2: G1+G2 fused (108 blocks) ----------------
// bid = nt + 12*my; my<8: token proj (TP); my==8: label proj (LP)
__global__ __launch_bounds__(256, 4) void k_mm1(
    const unsigned short* __restrict__ TC, const unsigned short* __restrict__ LC,
    const unsigned short* __restrict__ WtC, const unsigned short* __restrict__ WlC,
    const float* __restrict__ bt, const float* __restrict__ bl,
    unsigned short* __restrict__ TP, unsigned short* __restrict__ LP) {
  __shared__ __align__(16) unsigned short As[8 * 128 * 8];
  __shared__ __align__(16) unsigned short Bs[8 * 128 * 8];
  const int bid = blockIdx.x;
  const int nt = bid % 12, my = bid / 12;
  const bool tok = my < 8;
  const unsigned short* A = tok ? TC : LC;
  const unsigned short* Bt = tok ? WtC : WlC;
  const float* bias = tok ? bt : bl;
  unsigned short* C = tok ? TP : LP;
  const int NRA = tok ? 1024 : 64, MA = tok ? 1024 : 50;
  const int m0 = tok ? my * 128 : 0;
  const int ldc = NRA;
  const int n0 = nt * 128;

  f32x4 acc[4][4];
#pragma unroll
  for (int i = 0; i < 4; i++)
#pragma unroll
    for (int j = 0; j < 4; j++) acc[i][j] = (f32x4){0.f, 0.f, 0.f, 0.f};
  mm_kloop(A, NRA, MA, m0, Bt, H2, n0, As, Bs, acc);

  const int lane = threadIdx.x & 63, wave = threadIdx.x >> 6;
  const int q = lane >> 4, li = lane & 15;
  const int wm = (wave >> 1) * 64, wn = (wave & 1) * 64;
#pragma unroll
  for (int mi = 0; mi < 4; mi++)
#pragma unroll
    for (int rr = 0; rr < 4; rr++) {
      int row = m0 + wm + mi * 16 + q * 4 + rr;
      if (row < MA) {
#pragma unroll
        for (int ni = 0; ni < 4; ni++) {
          int col = n0 + wn + ni * 16 + li;
          C[((size_t)(col >> 3) * ldc + row) * 8 + (col & 7)] =
              f2bf(acc[mi][ni][rr] + bias[col]);
        }
      }
    }
}

// ---------------- K3: G3+G4 (216 blocks) + make_x (9600 blocks) ----------------
__global__ __launch_bounds__(256, 4) void k_mm2(
    const unsigned short* __restrict__ TP, const unsigned short* __restrict__ LP,
    const unsigned short* __restrict__ W1C,
    float* __restrict__ base, float* __restrict__ al,
    unsigned short* __restrict__ XC) {
  __shared__ __align__(16) unsigned short As[8 * 128 * 8];
  __shared__ __align__(16) unsigned short Bs[8 * 128 * 8];
  const int bid = blockIdx.x;
  if (bid < 216) {
    const int nt = bid % 24, my = bid / 24;
    const bool tok = my < 8;
    const unsigned short* A = tok ? TP : LP;
    const unsigned short* Bt = tok ? W1C : W1C + (size_t)96 * H4 * 8;
    float* Cf = tok ? base : al;
    const int NRA = tok ? 1024 : 64, MA = tok ? 1024 : 50;
    const int m0 = tok ? my * 128 : 0;
    const int n0 = nt * 128;

    f32x4 acc[4][4];
#pragma unroll
    for (int i = 0; i < 4; i++)
#pragma unroll
      for (int j = 0; j < 4; j++) acc[i][j] = (f32x4){0.f, 0.f, 0.f, 0.f};
    mm_kloop(A, NRA, MA, m0, Bt, H4, n0, As, Bs, acc);

    const int lane = threadIdx.x & 63, wave = threadIdx.x >> 6;
    const int q = lane >> 4, li = lane & 15;
    const int wm = (wave >> 1) * 64, wn = (wave & 1) * 64;
#pragma unroll
    for (int mi = 0; mi < 4; mi++)
#pragma unroll
      for (int rr = 0; rr < 4; rr++) {
        int row = m0 + wm + mi * 16 + q * 4 + rr;
        if (row < MA) {
#pragma unroll
          for (int ni = 0; ni < 4; ni++) {
            int col = n0 + wn + ni * 16 + li;
            Cf[(size_t)row * H4 + col] = acc[mi][ni][rr];
          }
        }
      }
  } else {
    // make_x: XC[bc][hc][s][8] = tb_chunk(96+hc)[b*512+s] * lb_chunk(96+hc)[bc]
    const int i = bid - 216;           // 0..9599
    const int bc = i / 192;
    const int rem = i % 192;
    const int hc = rem >> 1;
    const int s = (rem & 1) * 256 + threadIdx.x;
    const int b = bc / CC;
    bf16x8 tv = *(const bf16x8*)&TP[((size_t)(96 + hc) * 1024 + b * 512 + s) * 8];
    bf16x8 lv = *(const bf16x8*)&LP[((size_t)(96 + hc) * 64 + bc) * 8];
    bf16x8 o;
#pragma unroll
    for (int j = 0; j < 8; j++)
      o[j] = (short)f2bf(bf2f((unsigned short)tv[j]) * bf2f((unsigned short)lv[j]));
    *(bf16x8*)&XC[(size_t)bc * XC_STRIDE + ((size_t)hc * 512 + s) * 8] = o;
  }
}

// ---------------- K4: G5 scorer (grid 24 x 200) ----------------
__global__ __launch_bounds__(256, 4) void k_scorer(
    const unsigned short* __restrict__ XC,   // per-bc slabs [96][512][8]
    const unsigned short* __restrict__ Bt,   // W1p chunked [96][3072][8]
    const float* __restrict__ base, const float* __restrict__ al,
    const float* __restrict__ b1, const float* __restrict__ W2,
    float* __restrict__ out) {
  __shared__ __align__(16) unsigned short As[8 * 128 * 8];
  __shared__ __align__(16) unsigned short Bs[8 * 128 * 8];
  const int tid = threadIdx.x;
  const int lane = tid & 63;
  const int wave = tid >> 6;
  const int q = lane >> 4;
  const int li = lane & 15;
  const int wm = (wave >> 1) * 64;
  const int wn = (wave & 1) * 64;

  const int n0 = blockIdx.x * 128;
  const int bc = blockIdx.y >> 2;
  const int m0 = (blockIdx.y & 3) * 128;
  const unsigned short* Ab = XC + (size_t)bc * XC_STRIDE;

  f32x4 acc[4][4];
#pragma unroll
  for (int i = 0; i < 4; i++)
#pragma unroll
    for (int j = 0; j < 4; j++) acc[i][j] = (f32x4){0.f, 0.f, 0.f, 0.f};
  mm_kloop(Ab, 512, 512, m0, Bt, H4, n0, As, Bs, acc);

  // epilogue: E = acc + base + al + b1; relu; out += E @ W2 via MFMA
  const int b = bc / CC, c = bc % CC;
  int fcol[4];
  float alb[4];
#pragma unroll
  for (int ni = 0; ni < 4; ni++) {
    int f = n0 + wn + ni * 16 + li;
    fcol[ni] = f;
    alb[ni] = al[(size_t)bc * H4 + f] + b1[f];
  }
  bf16x8 w2f[2];
#pragma unroll
  for (int ks = 0; ks < 2; ks++)
#pragma unroll
    for (int jj = 0; jj < 8; jj++) {
      int f = n0 + wn + ks * 32 + q * 8 + jj;
      float v = (li < 3) ? W2[(size_t)f * 3 + li] : 0.f;
      w2f[ks][jj] = (short)f2bf(v);
    }
  unsigned short* Ew = (unsigned short*)((char*)As + wave * 2304);

#pragma unroll
  for (int mi = 0; mi < 4; mi++) {
    float bs[4][4];
#pragma unroll
    for (int rr = 0; rr < 4; rr++) {
      int s_l = m0 + wm + mi * 16 + q * 4 + rr;
      const float* bp = base + (size_t)(b * SS + s_l) * H4;
#pragma unroll
      for (int ni = 0; ni < 4; ni++) bs[ni][rr] = bp[fcol[ni]];
    }
#pragma unroll
    for (int rr = 0; rr < 4; rr++)
#pragma unroll
      for (int ni = 0; ni < 4; ni++) {
        float v = acc[mi][ni][rr] + bs[ni][rr] + alb[ni];
        v = fmaxf(v, 0.f);
        Ew[(q * 4 + rr) * 72 + ni * 16 + li] = f2bf(v);
      }
    f32x4 oc = (f32x4){0.f, 0.f, 0.f, 0.f};
#pragma unroll
    for (int ks = 0; ks < 2; ks++) {
      bf16x8 ef = *(const bf16x8*)&Ew[li * 72 + ks * 32 + q * 8];
      oc = __builtin_amdgcn_mfma_f32_16x16x32_bf16(ef, w2f[ks], oc, 0, 0, 0);
    }
#pragma unroll
    for (int rr = 0; rr < 4; rr++) {
      int s_l = m0 + wm + mi * 16 + q * 4 + rr;
      if (li < 3)
        atomicAdd(&out[((size_t)(b * SS + s_l) * CC + c) * 3 + li], oc[rr]);
    }
  }
}

// ---------------- host launch ----------------

extern "C" void kernel_launch(void* const* d_in, const int* in_sizes, int n_in,
                              void* d_out, int out_size, void* d_ws, size_t ws_size,
                              hipStream_t stream) {
  (void)in_sizes; (void)n_in; (void)ws_size; (void)out_size;
  const float* token = (const float*)d_in[0];
  const float* label = (const float*)d_in[1];
  const float* Wt    = (const float*)d_in[2];
  const float* bt    = (const float*)d_in[3];
  const float* Wl    = (const float*)d_in[4];
  const float* bl    = (const float*)d_in[5];
  const float* W1    = (const float*)d_in[6];
  const float* b1    = (const float*)d_in[7];
  const float* W2    = (const float*)d_in[8];
  const float* b2    = (const float*)d_in[9];
  float* out = (float*)d_out;

  char* p = (char*)d_ws;
  auto alloc = [&](size_t bytes) {
    char* r = p;
    p += (bytes + 255) & ~(size_t)255;
    return r;
  };
  unsigned short* TC  = (unsigned short*)alloc((size_t)96 * 1024 * 8 * 2);
  unsigned short* LC  = (unsigned short*)alloc((size_t)96 * 64 * 8 * 2);
  unsigned short* WtC = (unsigned short*)alloc((size_t)96 * 1536 * 8 * 2);
  unsigned short* WlC = (unsigned short*)alloc((size_t)96 * 1536 * 8 * 2);
  unsigned short* W1C = (unsigned short*)alloc((size_t)288 * 3072 * 8 * 2);
  unsigned short* TP  = (unsigned short*)alloc((size_t)192 * 1024 * 8 * 2);
  unsigned short* LP  = (unsigned short*)alloc((size_t)192 * 64 * 8 * 2);
  unsigned short* XC  = (unsigned short*)alloc((size_t)CC * BB * XC_STRIDE * 2);
  float* base = (float*)alloc((size_t)BB * SS * H4 * 4);
  float* al   = (float*)alloc((size_t)BB * CC * H4 * 4);

  // K1: all casts/chunking + out init
  k_prep<<<5316, 256, 0, stream>>>(token, label, b2, Wt, Wl, W1,
                                   TC, LC, out, WtC, WlC, W1C);
  // K2: G1+G2 fused projections
  k_mm1<<<108, 256, 0, stream>>>(TC, LC, WtC, WlC, bt, bl, TP, LP);
  // K3: G3+G4 GEMMs + make_x
  k_mm2<<<9816, 256, 0, stream>>>(TP, LP, W1C, base, al, XC);
  // K4: G5 scorer
  k_scorer<<<dim3(24, 200), 256, 0, stream>>>(
      XC, W1C + (size_t)192 * H4 * 8, base, al, b1, W2, out);
}